// Round 1
// baseline (3074.332 us; speedup 1.0000x reference)
//
#include <hip/hip_runtime.h>
#include <math.h>

#define D 64
#define RU 256

__device__ __forceinline__ float selu_f(float x) {
    // scale = 1.0507009873554805, scale*alpha = 1.7580993408473766
    return x > 0.0f ? 1.0507009873554805f * x : 1.7580993408473766f * expm1f(x);
}

// P = state @ W_msg[0:64,:], Q = state @ W_msg[64:128,:]
__global__ __launch_bounds__(256) void pq_kernel(
    const float* __restrict__ state, const float* __restrict__ W_msg,
    float* __restrict__ P, float* __restrict__ Q, int n_links)
{
    __shared__ float sWt[64 * 64];
    __shared__ float sWb[64 * 64];
    __shared__ float s_in[4][64];
    for (int i = threadIdx.x; i < 64 * 64; i += 256) {
        sWt[i] = W_msg[i];
        sWb[i] = W_msg[64 * 64 + i];
    }
    __syncthreads();
    const int slot = threadIdx.x >> 6;
    const int j = threadIdx.x & 63;
    const int ngroups = (n_links + 3) >> 2;
    for (int g = blockIdx.x; g < ngroups; g += gridDim.x) {
        const int l = g * 4 + slot;
        const bool valid = (l < n_links);
        s_in[slot][j] = valid ? state[(size_t)l * D + j] : 0.0f;
        __syncthreads();
        float p = 0.0f, q = 0.0f;
#pragma unroll 8
        for (int k = 0; k < 64; ++k) {
            const float x = s_in[slot][k];
            p += x * sWt[k * 64 + j];
            q += x * sWb[k * 64 + j];
        }
        if (valid) {
            P[(size_t)l * D + j] = p;
            Q[(size_t)l * D + j] = q;
        }
        __syncthreads();
    }
}

// per edge: msg = selu(P[first] + Q[second] + b_msg); h = relu(msg @ W_gcn + b_gcn);
// atomic scatter-add h onto out[second]
__global__ __launch_bounds__(256) void edge_kernel(
    const float* __restrict__ P, const float* __restrict__ Q,
    const int* __restrict__ first, const int* __restrict__ second,
    const float* __restrict__ b_msg,
    const float* __restrict__ W_gcn, const float* __restrict__ b_gcn,
    float* __restrict__ out, int n_edges)
{
    __shared__ float sW[64 * 64];
    __shared__ float sb_msg[64];
    __shared__ float sb_gcn[64];
    __shared__ float s_msg[4][64];
    for (int i = threadIdx.x; i < 64 * 64; i += 256) sW[i] = W_gcn[i];
    if (threadIdx.x < 64) {
        sb_msg[threadIdx.x] = b_msg[threadIdx.x];
        sb_gcn[threadIdx.x] = b_gcn[threadIdx.x];
    }
    __syncthreads();
    const int slot = threadIdx.x >> 6;
    const int j = threadIdx.x & 63;
    const int ngroups = (n_edges + 3) >> 2;
    for (int g = blockIdx.x; g < ngroups; g += gridDim.x) {
        const int e = g * 4 + slot;
        const bool valid = (e < n_edges);
        float msg = 0.0f;
        int si = 0;
        if (valid) {
            const int fi = first[e];
            si = second[e];
            const float x = P[(size_t)fi * D + j] + Q[(size_t)si * D + j] + sb_msg[j];
            msg = selu_f(x);
        }
        s_msg[slot][j] = msg;
        __syncthreads();
        float acc = sb_gcn[j];
#pragma unroll 16
        for (int k = 0; k < 64; ++k) acc += s_msg[slot][k] * sW[k * 64 + j];
        acc = fmaxf(acc, 0.0f);
        if (valid) atomicAdd(&out[(size_t)si * D + j], acc);
        __syncthreads();
    }
}

// graph_emb[gid[l]] += state[l]
__global__ __launch_bounds__(256) void graph_sum_kernel(
    const float* __restrict__ state, const int* __restrict__ gid,
    float* __restrict__ gemb, int n_links)
{
    const int total = n_links * D;
    for (int idx = blockIdx.x * blockDim.x + threadIdx.x; idx < total;
         idx += gridDim.x * blockDim.x) {
        const int l = idx >> 6;
        const int j = idx & 63;
        atomicAdd(&gemb[gid[l] * D + j], state[idx]);
    }
}

// out[g][j] = selu(dot(gemb[g], W[:,j]) + b[j]) ; K = 64, N = 256
__global__ __launch_bounds__(256) void r1_kernel(
    const float* __restrict__ gemb, const float* __restrict__ W,
    const float* __restrict__ b, float* __restrict__ out)
{
    __shared__ float s[64];
    const int g = blockIdx.x;
    const int j = threadIdx.x;
    if (j < 64) s[j] = gemb[g * D + j];
    __syncthreads();
    float acc = b[j];
#pragma unroll 8
    for (int k = 0; k < 64; ++k) acc += s[k] * W[k * RU + j];
    out[g * RU + j] = selu_f(acc);
}

// out[g][j] = selu(dot(r[g], W[:,j]) + b[j]) ; K = 256, N = 256
__global__ __launch_bounds__(256) void r2_kernel(
    const float* __restrict__ rin, const float* __restrict__ W,
    const float* __restrict__ b, float* __restrict__ out)
{
    __shared__ float s[RU];
    const int g = blockIdx.x;
    const int j = threadIdx.x;
    s[j] = rin[g * RU + j];
    __syncthreads();
    float acc = b[j];
#pragma unroll 8
    for (int k = 0; k < RU; ++k) acc += s[k] * W[k * RU + j];
    out[g * RU + j] = selu_f(acc);
}

// out[g] = dot(r2[g], W_r3) + b ; one block of 256 threads
__global__ __launch_bounds__(256) void r3_kernel(
    const float* __restrict__ rin, const float* __restrict__ W,
    const float* __restrict__ b, float* __restrict__ out)
{
    __shared__ float sW[RU];
    const int g = threadIdx.x;
    sW[g] = W[g];
    __syncthreads();
    float acc = 0.0f;
#pragma unroll 8
    for (int k = 0; k < RU; ++k) acc += rin[g * RU + k] * sW[k];
    out[g] = acc + b[0];
}

extern "C" void kernel_launch(void* const* d_in, const int* in_sizes, int n_in,
                              void* d_out, int out_size, void* d_ws, size_t ws_size,
                              hipStream_t stream)
{
    const float* states_action = (const float*)d_in[0];
    const float* W_msg = (const float*)d_in[1];
    const float* b_msg = (const float*)d_in[2];
    const float* W_gcn = (const float*)d_in[3];
    const float* b_gcn = (const float*)d_in[4];
    const float* W_r1 = (const float*)d_in[5];
    const float* b_r1 = (const float*)d_in[6];
    const float* W_r2 = (const float*)d_in[7];
    const float* b_r2 = (const float*)d_in[8];
    const float* W_r3 = (const float*)d_in[9];
    const float* b_r3 = (const float*)d_in[10];
    const int* gid = (const int*)d_in[11];
    const int* first = (const int*)d_in[12];
    const int* second = (const int*)d_in[13];

    const int n_links = in_sizes[0] / D;     // 100000
    const int n_edges = in_sizes[12];        // 1600000
    const int G = out_size;                  // 256

    const size_t state_bytes = (size_t)n_links * D * sizeof(float);
    char* ws = (char*)d_ws;
    float* S = (float*)ws;                               // rotating state buffer
    float* P = (float*)(ws + state_bytes);
    float* Q = (float*)(ws + 2 * state_bytes);
    float* gemb = (float*)(ws + 3 * state_bytes);        // G*64
    float* r1 = gemb + (size_t)G * D;                    // G*256
    float* r2 = r1 + (size_t)G * RU;                     // G*256

    const int pq_grid = 1024;
    const int edge_grid = 2048;

    const float* state_in = states_action;
    for (int t = 0; t < 4; ++t) {
        pq_kernel<<<pq_grid, 256, 0, stream>>>(state_in, W_msg, P, Q, n_links);
        // state_in's buffer (S after t=0) is dead once PQ is computed; reuse S as output
        hipMemsetAsync(S, 0, state_bytes, stream);
        edge_kernel<<<edge_grid, 256, 0, stream>>>(P, Q, first, second, b_msg,
                                                   W_gcn, b_gcn, S, n_edges);
        state_in = S;
    }

    hipMemsetAsync(gemb, 0, (size_t)G * D * sizeof(float), stream);
    graph_sum_kernel<<<2048, 256, 0, stream>>>(S, gid, gemb, n_links);
    r1_kernel<<<G, 256, 0, stream>>>(gemb, W_r1, b_r1, r1);
    r2_kernel<<<G, 256, 0, stream>>>(r1, W_r2, b_r2, r2);
    r3_kernel<<<1, 256, 0, stream>>>(r2, W_r3, b_r3, (float*)d_out);
}

// Round 2
// 1835.867 us; speedup vs baseline: 1.6746x; 1.6746x over previous
//
#include <hip/hip_runtime.h>
#include <math.h>

#define D 64
#define RU 256

typedef short bf16x8 __attribute__((ext_vector_type(8)));
typedef float f32x4 __attribute__((ext_vector_type(4)));

__device__ __forceinline__ float selu_f(float x) {
    return x > 0.0f ? 1.0507009873554805f * x : 1.7580993408473766f * expm1f(x);
}

__device__ __forceinline__ short f2bf(float x) {
    union { float f; unsigned u; } v; v.f = x;
    unsigned r = (v.u + 0x7FFFu + ((v.u >> 16) & 1u)) >> 16;
    return (short)r;
}
__device__ __forceinline__ float bf2f(short s) {
    union { float f; unsigned u; } v; v.u = ((unsigned)(unsigned short)s) << 16;
    return v.f;
}

// P = state @ W_msg[0:64,:], Q = state @ W_msg[64:128,:]
__global__ __launch_bounds__(256) void pq_kernel(
    const float* __restrict__ state, const float* __restrict__ W_msg,
    float* __restrict__ P, float* __restrict__ Q, int n_links)
{
    __shared__ float sWt[64 * 64];
    __shared__ float sWb[64 * 64];
    __shared__ float s_in[4][64];
    for (int i = threadIdx.x; i < 64 * 64; i += 256) {
        sWt[i] = W_msg[i];
        sWb[i] = W_msg[64 * 64 + i];
    }
    __syncthreads();
    const int slot = threadIdx.x >> 6;
    const int j = threadIdx.x & 63;
    const int ngroups = (n_links + 3) >> 2;
    for (int g = blockIdx.x; g < ngroups; g += gridDim.x) {
        const int l = g * 4 + slot;
        const bool valid = (l < n_links);
        s_in[slot][j] = valid ? state[(size_t)l * D + j] : 0.0f;
        __syncthreads();
        float p = 0.0f, q = 0.0f;
#pragma unroll 8
        for (int k = 0; k < 64; ++k) {
            const float x = s_in[slot][k];
            p += x * sWt[k * 64 + j];
            q += x * sWb[k * 64 + j];
        }
        if (valid) {
            P[(size_t)l * D + j] = p;
            Q[(size_t)l * D + j] = q;
        }
        __syncthreads();
    }
}

// MFMA edge kernel: msg = selu(P[first]+Q[second]+b_msg);
// h = relu(msg @ W_gcn + b_gcn); atomic scatter onto out[second].
// Wave handles 16 edges x 64 j. Split-bf16 (hi+lo) for ~fp32 accuracy.
__global__ __launch_bounds__(256) void edge_mfma_kernel(
    const float* __restrict__ P, const float* __restrict__ Q,
    const int* __restrict__ first, const int* __restrict__ second,
    const float* __restrict__ b_msg,
    const float* __restrict__ W_gcn, const float* __restrict__ b_gcn,
    float* __restrict__ out, int n_edges)
{
    const int tid = threadIdx.x;
    const int wave = tid >> 6;
    const int lane = tid & 63;
    const int m = lane & 15;   // edge-in-subtile (A rows) / col n (B, D)
    const int qd = lane >> 4;  // quad -> k-group

    // B fragments (W_gcn hi/lo) in registers for the whole kernel.
    // B[k][n]: n = lane&15, k = ks*32 + qd*8 + i
    bf16x8 Bh[2][4], Bl[2][4];
#pragma unroll
    for (int ks = 0; ks < 2; ++ks)
#pragma unroll
        for (int jt = 0; jt < 4; ++jt) {
            const int nn = jt * 16 + m;
#pragma unroll
            for (int i = 0; i < 8; ++i) {
                const int kk = ks * 32 + qd * 8 + i;
                const float w = W_gcn[kk * 64 + nn];
                const short hi = f2bf(w);
                Bh[ks][jt][i] = hi;
                Bl[ks][jt][i] = f2bf(w - bf2f(hi));
            }
        }
    float bias_msg[16];
#pragma unroll
    for (int i = 0; i < 8; ++i) {
        bias_msg[i] = b_msg[qd * 8 + i];
        bias_msg[8 + i] = b_msg[32 + qd * 8 + i];
    }
    float bias_gcn[4];
#pragma unroll
    for (int jt = 0; jt < 4; ++jt) bias_gcn[jt] = b_gcn[jt * 16 + m];

    const int tiles = (n_edges + 63) >> 6;
    for (int t = blockIdx.x; t < tiles; t += gridDim.x) {
        const int ebase = t * 64 + wave * 16;
        const int e = ebase + m;          // this lane's edge (same for all quads)
        const bool ev = (e < n_edges);
        int fi = 0, si = 0;
        if (ev) { fi = first[e]; si = second[e]; }

        // gather P/Q: this lane's 16 features j in {qd*8..+8} u {32+qd*8..+8}
        float pv[16], qv[16], msg[16];
        if (ev) {
            const float4* Pr = (const float4*)(P + (size_t)fi * D);
            const float4* Qr = (const float4*)(Q + (size_t)si * D);
            *(float4*)&pv[0]  = Pr[qd * 2];
            *(float4*)&pv[4]  = Pr[qd * 2 + 1];
            *(float4*)&pv[8]  = Pr[8 + qd * 2];
            *(float4*)&pv[12] = Pr[9 + qd * 2];
            *(float4*)&qv[0]  = Qr[qd * 2];
            *(float4*)&qv[4]  = Qr[qd * 2 + 1];
            *(float4*)&qv[8]  = Qr[8 + qd * 2];
            *(float4*)&qv[12] = Qr[9 + qd * 2];
#pragma unroll
            for (int i = 0; i < 16; ++i)
                msg[i] = selu_f(pv[i] + qv[i] + bias_msg[i]);
        } else {
#pragma unroll
            for (int i = 0; i < 16; ++i) msg[i] = 0.0f;
        }

        // A fragments (hi/lo): A[m][k], k = ks*32 + qd*8 + i
        bf16x8 Ah[2], Al[2];
#pragma unroll
        for (int ks = 0; ks < 2; ++ks)
#pragma unroll
            for (int i = 0; i < 8; ++i) {
                const float v = msg[ks * 8 + i];
                const short hi = f2bf(v);
                Ah[ks][i] = hi;
                Al[ks][i] = f2bf(v - bf2f(hi));
            }

        f32x4 acc[4];
#pragma unroll
        for (int jt = 0; jt < 4; ++jt) {
            const float b = bias_gcn[jt];
            acc[jt] = (f32x4){b, b, b, b};
#pragma unroll
            for (int ks = 0; ks < 2; ++ks) {
                acc[jt] = __builtin_amdgcn_mfma_f32_16x16x32_bf16(Ah[ks], Bh[ks][jt], acc[jt], 0, 0, 0);
                acc[jt] = __builtin_amdgcn_mfma_f32_16x16x32_bf16(Ah[ks], Bl[ks][jt], acc[jt], 0, 0, 0);
                acc[jt] = __builtin_amdgcn_mfma_f32_16x16x32_bf16(Al[ks], Bh[ks][jt], acc[jt], 0, 0, 0);
            }
        }

        // scatter: D[row][col]: col = lane&15 (=m), row = qd*4 + r
#pragma unroll
        for (int r = 0; r < 4; ++r) {
            const int row = qd * 4 + r;
            const int er = ebase + row;
            const int sr = __shfl(si, row, 64);
            if (er < n_edges) {
#pragma unroll
                for (int jt = 0; jt < 4; ++jt) {
                    const float h = fmaxf(acc[jt][r], 0.0f);
                    atomicAdd(&out[(size_t)sr * D + jt * 16 + m], h);
                }
            }
        }
    }
}

// graph_emb[gid[l]] += state[l]
__global__ __launch_bounds__(256) void graph_sum_kernel(
    const float* __restrict__ state, const int* __restrict__ gid,
    float* __restrict__ gemb, int n_links)
{
    const int total = n_links * D;
    for (int idx = blockIdx.x * blockDim.x + threadIdx.x; idx < total;
         idx += gridDim.x * blockDim.x) {
        const int l = idx >> 6;
        const int j = idx & 63;
        atomicAdd(&gemb[gid[l] * D + j], state[idx]);
    }
}

__global__ __launch_bounds__(256) void r1_kernel(
    const float* __restrict__ gemb, const float* __restrict__ W,
    const float* __restrict__ b, float* __restrict__ out)
{
    __shared__ float s[64];
    const int g = blockIdx.x;
    const int j = threadIdx.x;
    if (j < 64) s[j] = gemb[g * D + j];
    __syncthreads();
    float acc = b[j];
#pragma unroll 8
    for (int k = 0; k < 64; ++k) acc += s[k] * W[k * RU + j];
    out[g * RU + j] = selu_f(acc);
}

__global__ __launch_bounds__(256) void r2_kernel(
    const float* __restrict__ rin, const float* __restrict__ W,
    const float* __restrict__ b, float* __restrict__ out)
{
    __shared__ float s[RU];
    const int g = blockIdx.x;
    const int j = threadIdx.x;
    s[j] = rin[g * RU + j];
    __syncthreads();
    float acc = b[j];
#pragma unroll 8
    for (int k = 0; k < RU; ++k) acc += s[k] * W[k * RU + j];
    out[g * RU + j] = selu_f(acc);
}

__global__ __launch_bounds__(256) void r3_kernel(
    const float* __restrict__ rin, const float* __restrict__ W,
    const float* __restrict__ b, float* __restrict__ out)
{
    __shared__ float sW[RU];
    const int g = threadIdx.x;
    sW[g] = W[g];
    __syncthreads();
    float acc = 0.0f;
#pragma unroll 8
    for (int k = 0; k < RU; ++k) acc += rin[g * RU + k] * sW[k];
    out[g] = acc + b[0];
}

extern "C" void kernel_launch(void* const* d_in, const int* in_sizes, int n_in,
                              void* d_out, int out_size, void* d_ws, size_t ws_size,
                              hipStream_t stream)
{
    const float* states_action = (const float*)d_in[0];
    const float* W_msg = (const float*)d_in[1];
    const float* b_msg = (const float*)d_in[2];
    const float* W_gcn = (const float*)d_in[3];
    const float* b_gcn = (const float*)d_in[4];
    const float* W_r1 = (const float*)d_in[5];
    const float* b_r1 = (const float*)d_in[6];
    const float* W_r2 = (const float*)d_in[7];
    const float* b_r2 = (const float*)d_in[8];
    const float* W_r3 = (const float*)d_in[9];
    const float* b_r3 = (const float*)d_in[10];
    const int* gid = (const int*)d_in[11];
    const int* first = (const int*)d_in[12];
    const int* second = (const int*)d_in[13];

    const int n_links = in_sizes[0] / D;     // 100000
    const int n_edges = in_sizes[12];        // 1600000
    const int G = out_size;                  // 256

    const size_t state_bytes = (size_t)n_links * D * sizeof(float);
    char* ws = (char*)d_ws;
    float* S = (float*)ws;                               // rotating state buffer
    float* P = (float*)(ws + state_bytes);
    float* Q = (float*)(ws + 2 * state_bytes);
    float* gemb = (float*)(ws + 3 * state_bytes);        // G*64
    float* r1 = gemb + (size_t)G * D;                    // G*256
    float* r2 = r1 + (size_t)G * RU;                     // G*256

    const int pq_grid = 1024;
    const int edge_grid = 3072;

    const float* state_in = states_action;
    for (int t = 0; t < 4; ++t) {
        pq_kernel<<<pq_grid, 256, 0, stream>>>(state_in, W_msg, P, Q, n_links);
        hipMemsetAsync(S, 0, state_bytes, stream);
        edge_mfma_kernel<<<edge_grid, 256, 0, stream>>>(P, Q, first, second, b_msg,
                                                        W_gcn, b_gcn, S, n_edges);
        state_in = S;
    }

    hipMemsetAsync(gemb, 0, (size_t)G * D * sizeof(float), stream);
    graph_sum_kernel<<<2048, 256, 0, stream>>>(S, gid, gemb, n_links);
    r1_kernel<<<G, 256, 0, stream>>>(gemb, W_r1, b_r1, r1);
    r2_kernel<<<G, 256, 0, stream>>>(r1, W_r2, b_r2, r2);
    r3_kernel<<<1, 256, 0, stream>>>(r2, W_r3, b_r3, (float*)d_out);
}